// Round 2
// baseline (409.080 us; speedup 1.0000x reference)
//
#include <hip/hip_runtime.h>
#include <hip/hip_bf16.h>
#include <stdint.h>

typedef short bf16x8 __attribute__((ext_vector_type(8)));
typedef float f32x4  __attribute__((ext_vector_type(4)));

__device__ __forceinline__ unsigned short f2bf(float f) {  // RNE, finite inputs
  unsigned int u = __float_as_uint(f);
  u = (u + 0x7fffu + ((u >> 16) & 1u)) >> 16;
  return (unsigned short)u;
}
__device__ __forceinline__ float bf2f(unsigned short s) { return __uint_as_float(((unsigned int)s) << 16); }
__device__ __forceinline__ float bflo(unsigned int pr) { return __uint_as_float(pr << 16); }
__device__ __forceinline__ float bfhi(unsigned int pr) { return __uint_as_float(pr & 0xffff0000u); }

#define Nn 128
#define Dd 2048
#define DH 128
#define BK 64
#define HP 130   // padded bf16 row stride for h

// ---------------- kernel A: dtype probe (1 = fp32 inputs, 0 = bf16 inputs) ----
__global__ void detect_dtype(const unsigned int* __restrict__ X, int* __restrict__ flag) {
  if (threadIdx.x == 0) {
    int cnt = 0;
#pragma unroll
    for (int i = 0; i < 64; ++i) {
      unsigned int e = (X[i] >> 23) & 0xffu;   // f32 exponent field
      cnt += (e < 200u) ? 1 : 0;               // N(0,1) fp32: always; bf16-pairs: ~5%
    }
    *flag = (cnt >= 32) ? 1 : 0;
  }
}

// ---------------- kernel B: Wa[2048][128] -> WaT[128][2048] (always bf16 out) --
__global__ __launch_bounds__(256) void transpose_wa(const void* __restrict__ Wa,
                                                    short* __restrict__ WaT,
                                                    const int* __restrict__ flag) {
  const int f32 = *flag;
  __shared__ short tile[32][33];
  const int tx = threadIdx.x & 31, ty = threadIdx.x >> 5;
  const int d0 = blockIdx.x * 32, e0 = blockIdx.y * 32;
#pragma unroll
  for (int r = 0; r < 4; ++r) {
    const int src = (d0 + ty + 8 * r) * DH + e0 + tx;
    short v;
    if (f32) v = (short)f2bf(((const float*)Wa)[src]);
    else     v = ((const short*)Wa)[src];
    tile[ty + 8 * r][tx] = v;
  }
  __syncthreads();
#pragma unroll
  for (int r = 0; r < 4; ++r)
    WaT[(e0 + ty + 8 * r) * Dd + d0 + tx] = tile[tx][ty + 8 * r];
}

// ---------------- kernel C: fused GEMM + graph-attention epilogue -------------
union SMemU {
  struct { short A[128 * BK]; short Bm[128 * BK]; } st;  // 32 KB staging
  unsigned short h[128 * HP];                            // 33280 B bf16 h
};

template <bool F32>
__device__ __forceinline__ void gat_body(
    const void* __restrict__ Xv, const short* __restrict__ WaT,
    const void* __restrict__ Wb, const void* __restrict__ bbp,
    const void* __restrict__ Wc, const void* __restrict__ bcp,
    const void* __restrict__ biasp, void* __restrict__ outv,
    SMemU& sm, float* t1s, float* t2s, float* wbs, float* wcs,
    float* biass, float* red, float* mrec, float* srec)
{
  const int tid = threadIdx.x;
  const int b   = blockIdx.x;
  const int l   = tid & 63;
  const int w   = tid >> 6;
  const int wr  = w >> 1, wcol = w & 1;

  if (tid < 128) {
    wbs[tid]   = F32 ? ((const float*)Wb)[tid]    : bf2f(((const unsigned short*)Wb)[tid]);
    wcs[tid]   = F32 ? ((const float*)Wc)[tid]    : bf2f(((const unsigned short*)Wc)[tid]);
    biass[tid] = F32 ? ((const float*)biasp)[tid] : bf2f(((const unsigned short*)biasp)[tid]);
  }

  f32x4 acc[4][4];
#pragma unroll
  for (int i = 0; i < 4; ++i)
#pragma unroll
    for (int j = 0; j < 4; ++j) acc[i][j] = (f32x4){0.f, 0.f, 0.f, 0.f};

  const int rowi = tid >> 3;          // 0..31
  const int kofs = (tid & 7) * 8;     // 0..56
  short* As = sm.st.A;
  short* Bs = sm.st.Bm;
  const size_t xbase = (size_t)b * Nn * Dd;

  bf16x8 aV[4], bV[4];
  auto load_tiles = [&](int k0) {
#pragma unroll
    for (int c = 0; c < 4; ++c) {
      const int grow = (32 * c + rowi) * Dd + k0 + kofs;
      if (F32) {
        const float* p = (const float*)Xv + xbase + grow;
        float4 u0 = *(const float4*)p;
        float4 u1 = *(const float4*)(p + 4);
        bf16x8 t;
        t[0] = (short)f2bf(u0.x); t[1] = (short)f2bf(u0.y);
        t[2] = (short)f2bf(u0.z); t[3] = (short)f2bf(u0.w);
        t[4] = (short)f2bf(u1.x); t[5] = (short)f2bf(u1.y);
        t[6] = (short)f2bf(u1.z); t[7] = (short)f2bf(u1.w);
        aV[c] = t;
      } else {
        aV[c] = *(const bf16x8*)((const short*)Xv + xbase + grow);
      }
      bV[c] = *(const bf16x8*)(WaT + grow);   // WaT row = e, col = k (bf16)
    }
  };

  load_tiles(0);
  for (int k0 = 0; k0 < Dd; k0 += BK) {
    __syncthreads();                     // prev iteration's LDS reads done
#pragma unroll
    for (int c = 0; c < 4; ++c) {
      *(bf16x8*)&As[c * 2048 + tid * 8] = aV[c];
      *(bf16x8*)&Bs[c * 2048 + tid * 8] = bV[c];
    }
    __syncthreads();                     // staging visible
    if (k0 + BK < Dd) load_tiles(k0 + BK);   // prefetch overlaps MFMA below
#pragma unroll
    for (int ks = 0; ks < 2; ++ks) {
      bf16x8 aF[4], bF[4];
#pragma unroll
      for (int mr = 0; mr < 4; ++mr)
        aF[mr] = *(const bf16x8*)&As[(wr * 64 + mr * 16 + (l & 15)) * BK + ks * 32 + (l >> 4) * 8];
#pragma unroll
      for (int nc = 0; nc < 4; ++nc)
        bF[nc] = *(const bf16x8*)&Bs[(wcol * 64 + nc * 16 + (l & 15)) * BK + ks * 32 + (l >> 4) * 8];
#pragma unroll
      for (int mr = 0; mr < 4; ++mr)
#pragma unroll
        for (int nc = 0; nc < 4; ++nc)
          acc[mr][nc] = __builtin_amdgcn_mfma_f32_16x16x32_bf16(aF[mr], bF[nc], acc[mr][nc], 0, 0, 0);
    }
  }
  __syncthreads();   // ALL waves' MFMA LDS reads done before union reuse as h

  // ---- acc -> LDS h (bf16). C/D layout: col = l&15, row = (l>>4)*4 + r ----
#pragma unroll
  for (int mr = 0; mr < 4; ++mr) {
    const int row0 = wr * 64 + mr * 16 + (l >> 4) * 4;
#pragma unroll
    for (int nc = 0; nc < 4; ++nc) {
      const int col = wcol * 64 + nc * 16 + (l & 15);
#pragma unroll
      for (int r = 0; r < 4; ++r)
        sm.h[(row0 + r) * HP + col] = f2bf(acc[mr][nc][r]);
    }
  }
  __syncthreads();

  // ---- t1/t2: 256 threads = 256 row-dots ----
  {
    const int i = tid & 127;
    const float* wv = (tid < 128) ? wbs : wcs;
    const unsigned int* hr = (const unsigned int*)&sm.h[i * HP];
    float a0 = 0.f, a1 = 0.f;
#pragma unroll 4
    for (int e2 = 0; e2 < 64; ++e2) {
      const unsigned int pr = hr[e2];
      a0 += bflo(pr) * wv[2 * e2];
      a1 += bfhi(pr) * wv[2 * e2 + 1];
    }
    const void* bsel = (tid < 128) ? bbp : bcp;
    const float bbv = F32 ? ((const float*)bsel)[0] : bf2f(((const unsigned short*)bsel)[0]);
    const float t = a0 + a1 + bbv;
    if (tid < 128) t1s[i] = t; else t2s[i] = t;
  }
  __syncthreads();

  // ---- column softmax over i (axis=1), leaky_relu(0.2) ----
  {
    const int j  = tid & 127;
    const int hf = tid >> 7;
    const float t2j = t2s[j];
    float mloc = -1e30f;
#pragma unroll 4
    for (int ii = 0; ii < 64; ++ii) {
      float s = t1s[hf * 64 + ii] + t2j;
      s = (s > 0.f) ? s : 0.2f * s;
      mloc = fmaxf(mloc, s);
    }
    red[hf * 128 + j] = mloc;
    __syncthreads();
    const float mj = fmaxf(red[j], red[128 + j]);
    float sl = 0.f;
#pragma unroll 4
    for (int ii = 0; ii < 64; ++ii) {
      float s = t1s[hf * 64 + ii] + t2j;
      s = (s > 0.f) ? s : 0.2f * s;
      sl += __expf(s - mj);
    }
    __syncthreads();
    red[hf * 128 + j] = sl;
    __syncthreads();
    if (hf == 0) {
      mrec[j] = mj;
      srec[j] = 1.f / (red[j] + red[128 + j]);
    }
  }
  __syncthreads();

  // ---- output: out[b,i,j] = h*(1+p) + bias[j] ----
  {
    const int jp = (tid & 63) * 2;
    const int rq = tid >> 6;
    const float m0 = mrec[jp],     s0 = srec[jp];
    const float m1 = mrec[jp + 1], s1 = srec[jp + 1];
    const float u0 = t2s[jp], u1 = t2s[jp + 1];
    const float b0 = biass[jp], b1 = biass[jp + 1];
#pragma unroll 4
    for (int ii = 0; ii < 32; ++ii) {
      const int i = ii * 4 + rq;
      const float t1i = t1s[i];
      float sA = t1i + u0; sA = (sA > 0.f) ? sA : 0.2f * sA;
      float sB = t1i + u1; sB = (sB > 0.f) ? sB : 0.2f * sB;
      const float pA = __expf(sA - m0) * s0;
      const float pB = __expf(sB - m1) * s1;
      const unsigned int pr = *(const unsigned int*)&sm.h[i * HP + jp];
      const float oA = bflo(pr) * (1.f + pA) + b0;
      const float oB = bfhi(pr) * (1.f + pB) + b1;
      if (F32) {
        float2 v2; v2.x = oA; v2.y = oB;
        *(float2*)((float*)outv + (size_t)b * Nn * DH + i * DH + jp) = v2;
      } else {
        const unsigned int pk = (unsigned int)f2bf(oA) | ((unsigned int)f2bf(oB) << 16);
        *(unsigned int*)((unsigned short*)outv + (size_t)b * Nn * DH + i * DH + jp) = pk;
      }
    }
  }
}

__global__ __launch_bounds__(256, 1) void fused_gat(
    const void* __restrict__ X, const short* __restrict__ WaT,
    const void* __restrict__ Wb, const void* __restrict__ bb,
    const void* __restrict__ Wc, const void* __restrict__ bc,
    const void* __restrict__ bias, void* __restrict__ out,
    const int* __restrict__ flag)
{
  __shared__ SMemU sm;
  __shared__ float t1s[128], t2s[128], wbs[128], wcs[128], biass[128];
  __shared__ float red[256], mrec[128], srec[128];
  if (*flag)
    gat_body<true>(X, WaT, Wb, bb, Wc, bc, bias, out, sm, t1s, t2s, wbs, wcs, biass, red, mrec, srec);
  else
    gat_body<false>(X, WaT, Wb, bb, Wc, bc, bias, out, sm, t1s, t2s, wbs, wcs, biass, red, mrec, srec);
}

// ---------------- launcher ----------------
extern "C" void kernel_launch(void* const* d_in, const int* in_sizes, int n_in,
                              void* d_out, int out_size, void* d_ws, size_t ws_size,
                              hipStream_t stream) {
  const void* X    = d_in[0];
  const void* Wa   = d_in[1];
  const void* Wb   = d_in[2];
  const void* bb   = d_in[3];
  const void* Wc   = d_in[4];
  const void* bc   = d_in[5];
  const void* bias = d_in[6];
  short* WaT = (short*)d_ws;                              // 512 KB
  int*   flag = (int*)((char*)d_ws + (512 << 10));        // 4 B after WaT

  detect_dtype<<<1, 64, 0, stream>>>((const unsigned int*)X, flag);
  transpose_wa<<<dim3(64, 4), 256, 0, stream>>>(Wa, WaT, flag);
  fused_gat<<<256, 256, 0, stream>>>(X, WaT, Wb, bb, Wc, bc, bias, d_out, flag);
}

// Round 3
// 403.816 us; speedup vs baseline: 1.0130x; 1.0130x over previous
//
#include <hip/hip_runtime.h>
#include <hip/hip_bf16.h>
#include <stdint.h>

typedef short bf16x8 __attribute__((ext_vector_type(8)));
typedef float f32x4  __attribute__((ext_vector_type(4)));

#define Nn 128
#define Dd 2048
#define DH 128
#define BK 64
#define HP 130   // padded bf16 row stride for h tile

__device__ __forceinline__ unsigned short f2bf(float f) {  // RNE, finite
  unsigned int u = __float_as_uint(f);
  u = (u + 0x7fffu + ((u >> 16) & 1u)) >> 16;
  return (unsigned short)u;
}
__device__ __forceinline__ float bf2f(unsigned short s) { return __uint_as_float(((unsigned int)s) << 16); }
__device__ __forceinline__ float bflo(unsigned int p) { return __uint_as_float(p << 16); }
__device__ __forceinline__ float bfhi(unsigned int p) { return __uint_as_float(p & 0xffff0000u); }

// fp32 N(0,1): f32 exponent field < 200 always. bf16 pairs misread as f32:
// exponent field >= 200 for ~95% of values.
__device__ __forceinline__ int detect_f32(const unsigned int* __restrict__ X) {
  int cnt = 0;
#pragma unroll
  for (int i = 0; i < 64; ++i) {
    unsigned int e = (X[i] >> 23) & 0xffu;
    cnt += (e < 200u) ? 1 : 0;
  }
  return cnt >= 32;
}

// ---------------- Wa[2048][128] -> WaT[128][2048] bf16 (self-detecting) ------
__global__ __launch_bounds__(256) void transpose_wa(const void* __restrict__ Wa,
                                                    short* __restrict__ WaT,
                                                    const unsigned int* __restrict__ X) {
  __shared__ int flg;
  __shared__ short tile[32][33];
  if (threadIdx.x == 0) flg = detect_f32(X);
  __syncthreads();
  const int f32 = flg;
  const int tx = threadIdx.x & 31, ty = threadIdx.x >> 5;
  const int d0 = blockIdx.x * 32, e0 = blockIdx.y * 32;
#pragma unroll
  for (int r = 0; r < 4; ++r) {
    const int src = (d0 + ty + 8 * r) * DH + e0 + tx;
    short v;
    if (f32) v = (short)f2bf(((const float*)Wa)[src]);
    else     v = ((const short*)Wa)[src];
    tile[ty + 8 * r][tx] = v;
  }
  __syncthreads();
#pragma unroll
  for (int r = 0; r < 4; ++r)
    WaT[(e0 + ty + 8 * r) * Dd + d0 + tx] = tile[tx][ty + 8 * r];
}

// ---------------- fused GEMM + graph-attention epilogue ----------------------
union SMemU {
  struct { short A[2][128 * BK]; short Bm[2][128 * BK]; } st;  // 64 KB double-buffer
  unsigned short h[128 * HP];                                  // 33280 B bf16 h
};

template <bool F32>
__device__ __forceinline__ void gat_body(
    const void* __restrict__ Xv, const short* __restrict__ WaT,
    const void* __restrict__ Wb, const void* __restrict__ bbp,
    const void* __restrict__ Wc, const void* __restrict__ bcp,
    const void* __restrict__ biasp, void* __restrict__ outv)
{
  __shared__ SMemU sm;
  __shared__ float t1s[128], t2s[128], wbs[128], wcs[128], biass[128];
  __shared__ float red[512];
  __shared__ float mrec[128], srec[128];
  __shared__ int flg;

  const int tid = threadIdx.x;
  if (tid == 0) flg = detect_f32((const unsigned int*)Xv);
  __syncthreads();
  if ((flg != 0) != F32) return;   // block-uniform early exit (wrong-dtype kernel)

  const int b   = blockIdx.x;
  const int l   = tid & 63;
  const int w   = tid >> 6;        // 0..7
  const int wr  = w >> 2;          // 0..1  (64-row slab)
  const int wc4 = w & 3;           // 0..3  (32-col slab)

  if (tid < 128) {
    wbs[tid]   = F32 ? ((const float*)Wb)[tid]    : bf2f(((const unsigned short*)Wb)[tid]);
    wcs[tid]   = F32 ? ((const float*)Wc)[tid]    : bf2f(((const unsigned short*)Wc)[tid]);
    biass[tid] = F32 ? ((const float*)biasp)[tid] : bf2f(((const unsigned short*)biasp)[tid]);
  }

  f32x4 acc[4][2];
#pragma unroll
  for (int i = 0; i < 4; ++i)
#pragma unroll
    for (int j = 0; j < 2; ++j) acc[i][j] = (f32x4){0.f, 0.f, 0.f, 0.f};

  const int rowh = tid >> 3;       // 0..63
  const int g    = tid & 7;        // 16B group within a 64-short row
  const size_t xbase = (size_t)b * Nn * Dd;

  float4 pa4[2][2];
  bf16x8 paB[2];
  bf16x8 pb[2];

  auto load_g = [&](int k0) {
#pragma unroll
    for (int c = 0; c < 2; ++c) {
      const int row = c * 64 + rowh;
      const int off = row * Dd + k0 + g * 8;
      if (F32) {
        const float* p = (const float*)Xv + xbase + off;
        pa4[c][0] = *(const float4*)p;
        pa4[c][1] = *(const float4*)(p + 4);
      } else {
        paB[c] = *(const bf16x8*)((const short*)Xv + xbase + off);
      }
      pb[c] = *(const bf16x8*)(WaT + off);
    }
  };

  auto store_lds = [&](int p) {
#pragma unroll
    for (int c = 0; c < 2; ++c) {
      const int row  = c * 64 + rowh;
      const int phys = row * 64 + ((g ^ (row & 7)) << 3);   // XOR-swizzled 16B group
      bf16x8 av;
      if (F32) {
        av[0] = (short)f2bf(pa4[c][0].x); av[1] = (short)f2bf(pa4[c][0].y);
        av[2] = (short)f2bf(pa4[c][0].z); av[3] = (short)f2bf(pa4[c][0].w);
        av[4] = (short)f2bf(pa4[c][1].x); av[5] = (short)f2bf(pa4[c][1].y);
        av[6] = (short)f2bf(pa4[c][1].z); av[7] = (short)f2bf(pa4[c][1].w);
      } else {
        av = paB[c];
      }
      *(bf16x8*)&sm.st.A[p][phys]  = av;
      *(bf16x8*)&sm.st.Bm[p][phys] = pb[c];
    }
  };

  auto mfma_step = [&](int p) {
#pragma unroll
    for (int ks = 0; ks < 2; ++ks) {
      const int gb = ks * 4 + (l >> 4);
      bf16x8 aF[4], bF[2];
#pragma unroll
      for (int mr = 0; mr < 4; ++mr) {
        const int row = wr * 64 + mr * 16 + (l & 15);
        aF[mr] = *(const bf16x8*)&sm.st.A[p][row * 64 + ((gb ^ (row & 7)) << 3)];
      }
#pragma unroll
      for (int nc = 0; nc < 2; ++nc) {
        const int row = wc4 * 32 + nc * 16 + (l & 15);
        bF[nc] = *(const bf16x8*)&sm.st.Bm[p][row * 64 + ((gb ^ (row & 7)) << 3)];
      }
#pragma unroll
      for (int mr = 0; mr < 4; ++mr)
#pragma unroll
        for (int nc = 0; nc < 2; ++nc)
          acc[mr][nc] = __builtin_amdgcn_mfma_f32_16x16x32_bf16(aF[mr], bF[nc], acc[mr][nc], 0, 0, 0);
    }
  };

  // single-barrier, double-buffered pipeline; global prefetch 1 iter ahead
  load_g(0);
  store_lds(0);
  load_g(BK);
  __syncthreads();
  int p = 0;
  for (int k0 = 0; k0 < Dd; k0 += BK) {
    mfma_step(p);
    if (k0 + BK < Dd) {
      store_lds(p ^ 1);                       // tile k0+BK (regs from last load_g)
      if (k0 + 2 * BK < Dd) load_g(k0 + 2 * BK);
    }
    __syncthreads();                          // buf p reads done; buf p^1 visible
    p ^= 1;
  }

  // ---- acc -> LDS h (bf16). C/D layout: col = l&15, row = (l>>4)*4 + r ----
#pragma unroll
  for (int mr = 0; mr < 4; ++mr) {
    const int row0 = wr * 64 + mr * 16 + (l >> 4) * 4;
#pragma unroll
    for (int nc = 0; nc < 2; ++nc) {
      const int col = wc4 * 32 + nc * 16 + (l & 15);
#pragma unroll
      for (int r = 0; r < 4; ++r)
        sm.h[(row0 + r) * HP + col] = f2bf(acc[mr][nc][r]);
    }
  }
  __syncthreads();

  // ---- t1/t2 row-dots: 512 threads, 2 per row per vector ----
  {
    const int i    = (tid >> 1) & 127;
    const int half = tid & 1;
    const float* wv = ((tid < 256) ? wbs : wcs) + half * 64;
    const unsigned int* hr = (const unsigned int*)&sm.h[i * HP] + half * 32;
    float a0 = 0.f, a1 = 0.f;
#pragma unroll 8
    for (int e2 = 0; e2 < 32; ++e2) {
      const unsigned int pr = hr[e2];
      a0 += bflo(pr) * wv[2 * e2];
      a1 += bfhi(pr) * wv[2 * e2 + 1];
    }
    red[tid] = a0 + a1;
  }
  __syncthreads();
  if (tid < 256) {
    const int j = tid & 127;
    const int sel = tid >> 7;
    const void* bsel = sel ? bcp : bbp;
    const float bv = F32 ? ((const float*)bsel)[0] : bf2f(((const unsigned short*)bsel)[0]);
    const float t = red[sel * 256 + 2 * j] + red[sel * 256 + 2 * j + 1] + bv;
    if (sel == 0) t1s[j] = t; else t2s[j] = t;
  }
  __syncthreads();

  // ---- column softmax over i (axis=1), leaky_relu(0.2); 4 threads/column ----
  {
    const int j  = tid & 127;
    const int hf = tid >> 7;           // 0..3, 32 rows each
    const float t2j = t2s[j];
    float mloc = -1e30f;
#pragma unroll 8
    for (int ii = 0; ii < 32; ++ii) {
      float s = t1s[hf * 32 + ii] + t2j;
      s = (s > 0.f) ? s : 0.2f * s;
      mloc = fmaxf(mloc, s);
    }
    red[hf * 128 + j] = mloc;
    __syncthreads();
    const float mj = fmaxf(fmaxf(red[j], red[128 + j]), fmaxf(red[256 + j], red[384 + j]));
    float sl = 0.f;
#pragma unroll 8
    for (int ii = 0; ii < 32; ++ii) {
      float s = t1s[hf * 32 + ii] + t2j;
      s = (s > 0.f) ? s : 0.2f * s;
      sl += __expf(s - mj);
    }
    __syncthreads();                    // all reads of red-as-max done
    red[hf * 128 + j] = sl;
    __syncthreads();
    if (hf == 0) {
      mrec[j] = mj;
      srec[j] = 1.f / (red[j] + red[128 + j] + red[256 + j] + red[384 + j]);
    }
  }
  __syncthreads();

  // ---- output: out[b,i,j] = h*(1+p) + bias[j]; 2 cols x 16 rows per thread --
  {
    const int jp = (tid & 63) * 2;
    const int rq = tid >> 6;           // 0..7 row phase (wave-uniform)
    const float m0 = mrec[jp],     s0 = srec[jp];
    const float m1 = mrec[jp + 1], s1 = srec[jp + 1];
    const float u0 = t2s[jp], u1 = t2s[jp + 1];
    const float b0 = biass[jp], b1 = biass[jp + 1];
#pragma unroll 4
    for (int ii = 0; ii < 16; ++ii) {
      const int i = ii * 8 + rq;
      const float t1i = t1s[i];
      float sA = t1i + u0; sA = (sA > 0.f) ? sA : 0.2f * sA;
      float sB = t1i + u1; sB = (sB > 0.f) ? sB : 0.2f * sB;
      const float pA = __expf(sA - m0) * s0;
      const float pB = __expf(sB - m1) * s1;
      const unsigned int pr = *(const unsigned int*)&sm.h[i * HP + jp];
      const float oA = bflo(pr) * (1.f + pA) + b0;
      const float oB = bfhi(pr) * (1.f + pB) + b1;
      if (F32) {
        float2 v2; v2.x = oA; v2.y = oB;
        *(float2*)((float*)outv + (size_t)b * Nn * DH + i * DH + jp) = v2;
      } else {
        const unsigned int pk = (unsigned int)f2bf(oA) | ((unsigned int)f2bf(oB) << 16);
        *(unsigned int*)((unsigned short*)outv + (size_t)b * Nn * DH + i * DH + jp) = pk;
      }
    }
  }
}

__global__ __launch_bounds__(512, 2) void fused_gat_f32(
    const void* __restrict__ X, const short* __restrict__ WaT,
    const void* __restrict__ Wb, const void* __restrict__ bb,
    const void* __restrict__ Wc, const void* __restrict__ bc,
    const void* __restrict__ bias, void* __restrict__ out) {
  gat_body<true>(X, WaT, Wb, bb, Wc, bc, bias, out);
}

__global__ __launch_bounds__(512, 2) void fused_gat_bf16(
    const void* __restrict__ X, const short* __restrict__ WaT,
    const void* __restrict__ Wb, const void* __restrict__ bb,
    const void* __restrict__ Wc, const void* __restrict__ bc,
    const void* __restrict__ bias, void* __restrict__ out) {
  gat_body<false>(X, WaT, Wb, bb, Wc, bc, bias, out);
}

// ---------------- launcher ----------------
extern "C" void kernel_launch(void* const* d_in, const int* in_sizes, int n_in,
                              void* d_out, int out_size, void* d_ws, size_t ws_size,
                              hipStream_t stream) {
  const void* X    = d_in[0];
  const void* Wa   = d_in[1];
  const void* Wb   = d_in[2];
  const void* bb   = d_in[3];
  const void* Wc   = d_in[4];
  const void* bc   = d_in[5];
  const void* bias = d_in[6];
  short* WaT = (short*)d_ws;   // 512 KB

  transpose_wa<<<dim3(64, 4), 256, 0, stream>>>(Wa, WaT, (const unsigned int*)X);
  fused_gat_f32 <<<256, 512, 0, stream>>>(X, WaT, Wb, bb, Wc, bc, bias, d_out);
  fused_gat_bf16<<<256, 512, 0, stream>>>(X, WaT, Wb, bb, Wc, bc, bias, d_out);
}